// Round 3
// baseline (317.128 us; speedup 1.0000x reference)
//
#include <hip/hip_runtime.h>

// GNNBackbone: B=4096 players, 64 asteroids each, HID=64, HEADS=4, OUT=64, L=2.
// edge e: asteroid (64p+j) -> player p  => fully player-local; 1 block/player,
// both layers fused, nothing in HBM except the final [B,64] output.
//
// Round-3: evidence (R1 all-NaN under bf16 reads; R2 finite unit-scale garbage
// = bf16-pair-packed floats) says inputs/output are FLOAT32. Output dtype now
// follows the sniffed input dtype. Internal compute: bf16 MFMA, f32 everywhere
// else (within the 2% threshold).

typedef __bf16 bf16x8 __attribute__((ext_vector_type(8)));
typedef float  f32x4  __attribute__((ext_vector_type(4)));

union FragU { unsigned short u[8]; bf16x8 v; };

__device__ __forceinline__ float bf2f(unsigned short u) {
    union { unsigned int i; float f; } v; v.i = ((unsigned int)u) << 16; return v.f;
}
__device__ __forceinline__ unsigned short f2bf(float f) {
    union { float f; unsigned int i; } v; v.f = f;
    unsigned int r = v.i + 0x7fffu + ((v.i >> 16) & 1u);
    return (unsigned short)(r >> 16);
}

__device__ __forceinline__ float ldv(const unsigned short* p, int i) { return bf2f(p[i]); }
__device__ __forceinline__ float ldv(const float* p, int i) { return p[i]; }
__device__ __forceinline__ unsigned short ldbf(const unsigned short* p, int i) { return p[i]; }
__device__ __forceinline__ unsigned short ldbf(const float* p, int i) { return f2bf(p[i]); }

struct Smem {
    __align__(16) unsigned short xa[64 * 112];   // [x(64) | ea(7) | zeros] per row
    __align__(16) unsigned short wetp[256 * 32]; // We^T padded: [c][k], k 7..31 = 0
    float xp[64];
    float xr[256];
    float att[256];
    float outp[256];
};

#define NEG_SLOPE 0.2f
#define LN_EPS 1e-5f

template <typename T>
__device__ __forceinline__ void body(
    const T* pf, const T* af, const T* eat, const T* Wp, const T* bp,
    const T* Wa, const T* ba, const T* Wl, const T* bl, const T* Wr,
    const T* br, const T* We, const T* att, const T* bias, const T* lng,
    const T* lnb, void* outv, Smem& sm, int p, int t)
{
    const int w = t >> 6;        // wave = head
    const int l = t & 63;        // lane
    const int q = l >> 4;        // k-group
    const int m = l & 15;        // col-within-tile

    // ---------- Phase 0: input projections ----------
    if (t < 64) {
        float acc = ldv(bp, t);
        #pragma unroll
        for (int d = 0; d < 5; ++d) acc += ldv(pf, p * 5 + d) * ldv(Wp, d * 64 + t);
        sm.xp[t] = fmaxf(acc, 0.f);
    }
    for (int idx = t; idx < 4096; idx += 256) {       // xa cols 0..63
        int j = idx >> 6, k = idx & 63;
        float acc = ldv(ba, k);
        #pragma unroll
        for (int d = 0; d < 3; ++d) acc += ldv(af, (p * 64 + j) * 3 + d) * ldv(Wa, d * 64 + k);
        sm.xa[j * 112 + k] = f2bf(fmaxf(acc, 0.f));
    }
    for (int idx = t; idx < 512; idx += 256) {        // cols 64..71 (ea, col71=0)
        int j = idx >> 3, d = idx & 7;
        sm.xa[j * 112 + 64 + d] = (d < 7) ? f2bf(ldv(eat, (p * 64 + j) * 7 + d))
                                          : (unsigned short)0;
    }
    for (int idx = t; idx < 2560; idx += 256) {       // cols 72..111 zero
        int j = idx / 40, cc = idx - j * 40;
        sm.xa[j * 112 + 72 + cc] = 0;
    }
    __syncthreads();

    const int cbase = w * 64;
    f32x4 accT[16];

    for (int layer = 0; layer < 2; ++layer) {
        // ---------- staging: wetp (We^T zero-padded), att, xr = xp@Wr + br ----------
        for (int idx = t; idx < 8192; idx += 256) {
            int c = idx >> 5, k = idx & 31;
            sm.wetp[idx] = (k < 7) ? ldbf(We, layer * 1792 + k * 256 + c)
                                   : (unsigned short)0;
        }
        sm.att[t] = ldv(att, layer * 256 + t);
        {
            float acc = ldv(br, layer * 256 + t);
            #pragma unroll
            for (int k = 0; k < 64; ++k)
                acc += sm.xp[k] * ldv(Wr, layer * 16384 + k * 256 + t);
            sm.xr[t] = acc;
        }
        __syncthreads();

        // ---------- per-lane fragments ----------
        FragU bfr[8]; // Wl B-frags [nt][ko]: lane(q,m) holds Wl[k=kb+jj][c]
        #pragma unroll
        for (int nt = 0; nt < 4; ++nt) {
            int c = cbase + nt * 16 + m;
            #pragma unroll
            for (int ko = 0; ko < 2; ++ko) {
                int kb = ko * 32 + q * 8;
                #pragma unroll
                for (int jj = 0; jj < 8; ++jj)
                    bfr[nt * 2 + ko].u[jj] = ldbf(Wl, layer * 16384 + (kb + jj) * 256 + c);
            }
        }
        bf16x8 ebf[4];
        float blc[4], xrc[4], aoc[4];
        #pragma unroll
        for (int nt = 0; nt < 4; ++nt) {
            int c = cbase + nt * 16 + m;
            ebf[nt] = *reinterpret_cast<const bf16x8*>(&sm.wetp[c * 32 + q * 8]);
            blc[nt] = ldv(bl, layer * 256 + c);
            xrc[nt] = sm.xr[c];
            aoc[nt] = sm.att[c];
        }

        // ---------- MFMA: xl = xa@Wl + bl ; e2 = ea@We + xr(+br) ----------
        float lp[16];
        #pragma unroll
        for (int i = 0; i < 16; ++i) lp[i] = 0.f;

        #pragma unroll
        for (int mt = 0; mt < 4; ++mt) {
            const int row = mt * 16 + m;
            bf16x8 a0 = *reinterpret_cast<const bf16x8*>(&sm.xa[row * 112 + q * 8]);
            bf16x8 a1 = *reinterpret_cast<const bf16x8*>(&sm.xa[row * 112 + 32 + q * 8]);
            bf16x8 a2 = *reinterpret_cast<const bf16x8*>(&sm.xa[row * 112 + 64 + q * 8]);
            #pragma unroll
            for (int nt = 0; nt < 4; ++nt) {
                f32x4 c1 = { blc[nt], blc[nt], blc[nt], blc[nt] };
                c1 = __builtin_amdgcn_mfma_f32_16x16x32_bf16(a0, bfr[nt * 2 + 0].v, c1, 0, 0, 0);
                c1 = __builtin_amdgcn_mfma_f32_16x16x32_bf16(a1, bfr[nt * 2 + 1].v, c1, 0, 0, 0);
                accT[mt * 4 + nt] = c1;   // pure xl (+bl) for messages
                f32x4 c2 = { xrc[nt], xrc[nt], xrc[nt], xrc[nt] };
                c2 = __builtin_amdgcn_mfma_f32_16x16x32_bf16(a2, ebf[nt], c2, 0, 0, 0);
                #pragma unroll
                for (int r = 0; r < 4; ++r) {
                    float ev = c1[r] + c2[r];
                    ev = (ev >= 0.f) ? ev : NEG_SLOPE * ev;
                    lp[mt * 4 + r] += ev * aoc[nt];
                }
            }
        }

        // att-dot: reduce over 16 m-lanes; lp[i] -> logit[j = mt*16 + q*4 + r]
        #pragma unroll
        for (int i = 0; i < 16; ++i) {
            float v = lp[i];
            v += __shfl_xor(v, 1, 64);
            v += __shfl_xor(v, 2, 64);
            v += __shfl_xor(v, 4, 64);
            v += __shfl_xor(v, 8, 64);
            lp[i] = v;
        }
        // softmax over all 64 j
        float mx = lp[0];
        #pragma unroll
        for (int i = 1; i < 16; ++i) mx = fmaxf(mx, lp[i]);
        mx = fmaxf(mx, __shfl_xor(mx, 16, 64));
        mx = fmaxf(mx, __shfl_xor(mx, 32, 64));
        float den = 0.f;
        #pragma unroll
        for (int i = 0; i < 16; ++i) { lp[i] = __expf(lp[i] - mx); den += lp[i]; }
        den += __shfl_xor(den, 16, 64);
        den += __shfl_xor(den, 32, 64);
        const float rden = 1.f / den;

        // weighted message sum: out[w][c] = sum_j alpha[j] * xl[j][c]
        #pragma unroll
        for (int nt = 0; nt < 4; ++nt) {
            float s = 0.f;
            #pragma unroll
            for (int mt = 0; mt < 4; ++mt) {
                f32x4 c = accT[mt * 4 + nt];
                #pragma unroll
                for (int r = 0; r < 4; ++r) s += lp[mt * 4 + r] * c[r];
            }
            s *= rden;
            s += __shfl_xor(s, 16, 64);
            s += __shfl_xor(s, 32, 64);
            if (q == 0) sm.outp[cbase + nt * 16 + m] = s;
        }
        __syncthreads();

        // ---------- asteroid update (needed only after layer 0) ----------
        if (layer == 0) {
            float rb = fmaxf(ldv(bias, l), 0.f);
            float g = ldv(lng, l), bb = ldv(lnb, l);
            #pragma unroll
            for (int s16 = 0; s16 < 16; ++s16) {
                int j = w * 16 + s16;
                float v = bf2f(sm.xa[j * 112 + l]) + rb;
                float sum = v, sq = v * v;
                #pragma unroll
                for (int msk = 1; msk <= 32; msk <<= 1) {
                    sum += __shfl_xor(sum, msk, 64);
                    sq  += __shfl_xor(sq,  msk, 64);
                }
                float mu = sum * (1.f / 64.f);
                float var = sq * (1.f / 64.f) - mu * mu;
                float y = (v - mu) * rsqrtf(var + LN_EPS) * g + bb;
                sm.xa[j * 112 + l] = f2bf(y);
            }
        }
        // ---------- player update ----------
        if (t < 64) {
            float xnew = 0.25f * (sm.outp[t] + sm.outp[64 + t] + sm.outp[128 + t] + sm.outp[192 + t])
                       + ldv(bias, layer * 64 + t);
            float v = sm.xp[t] + fmaxf(xnew, 0.f);
            float sum = v, sq = v * v;
            #pragma unroll
            for (int msk = 1; msk <= 32; msk <<= 1) {
                sum += __shfl_xor(sum, msk, 64);
                sq  += __shfl_xor(sq,  msk, 64);
            }
            float mu = sum * (1.f / 64.f);
            float var = sq * (1.f / 64.f) - mu * mu;
            float y = (v - mu) * rsqrtf(var + LN_EPS) * ldv(lng, layer * 64 + t)
                    + ldv(lnb, layer * 64 + t);
            sm.xp[t] = y;
        }
        __syncthreads();
    }

    if (t < 64) {
        float y = sm.xp[t];
        if (!(y == y) || y > 1e30f || y < -1e30f) y = 1e6f;  // NaN diagnostic signature
        if constexpr (__is_same(T, float)) {
            ((float*)outv)[p * 64 + t] = y;          // f32 inputs -> f32 output
        } else {
            ((unsigned short*)outv)[p * 64 + t] = f2bf(y);  // bf16 in -> bf16 out
        }
    }
}

__global__ __launch_bounds__(256) void gnn_fused(
    const void* pf, const void* af, const void* eat, const void* Wp, const void* bp,
    const void* Wa, const void* ba, const void* Wl, const void* bl, const void* Wr,
    const void* br, const void* We, const void* att, const void* bias,
    const void* lng, const void* lnb, void* out)
{
    __shared__ Smem sm;
    const int p = blockIdx.x, t = threadIdx.x;

    // dtype sniff: decode first 64 shorts of Wa as bf16. bf16 weights decode
    // to ~0.1-scale values; f32 bit-halves decode to huge/NaN bf16 with
    // P ≈ 1 - 5e-9. Block-uniform, so no divergence.
    bool f32m = false;
    const unsigned short* ws = (const unsigned short*)Wa;
    for (int i = 0; i < 64; ++i) {
        float v = bf2f(ws[i]);
        if (!(v > -1e4f && v < 1e4f)) f32m = true;
    }

    if (f32m)
        body<float>((const float*)pf, (const float*)af, (const float*)eat,
                    (const float*)Wp, (const float*)bp, (const float*)Wa,
                    (const float*)ba, (const float*)Wl, (const float*)bl,
                    (const float*)Wr, (const float*)br, (const float*)We,
                    (const float*)att, (const float*)bias, (const float*)lng,
                    (const float*)lnb, out, sm, p, t);
    else
        body<unsigned short>((const unsigned short*)pf, (const unsigned short*)af,
                    (const unsigned short*)eat, (const unsigned short*)Wp,
                    (const unsigned short*)bp, (const unsigned short*)Wa,
                    (const unsigned short*)ba, (const unsigned short*)Wl,
                    (const unsigned short*)bl, (const unsigned short*)Wr,
                    (const unsigned short*)br, (const unsigned short*)We,
                    (const unsigned short*)att, (const unsigned short*)bias,
                    (const unsigned short*)lng, (const unsigned short*)lnb,
                    out, sm, p, t);
}

extern "C" void kernel_launch(void* const* d_in, const int* in_sizes, int n_in,
                              void* d_out, int out_size, void* d_ws, size_t ws_size,
                              hipStream_t stream) {
    const int B = in_sizes[0] / 5;  // 4096 players
    // d_in[2] = edge_index (int32): src=arange(E), dst=src//64 — structural, unused.
    gnn_fused<<<dim3(B), dim3(256), 0, stream>>>(
        d_in[0], d_in[1], d_in[3], d_in[4], d_in[5], d_in[6], d_in[7],
        d_in[8], d_in[9], d_in[10], d_in[11], d_in[12], d_in[13], d_in[14],
        d_in[15], d_in[16], d_out);
}

// Round 4
// 203.159 us; speedup vs baseline: 1.5610x; 1.5610x over previous
//
#include <hip/hip_runtime.h>

// GNNBackbone: B=4096 players, 64 asteroids each, HID=64, HEADS=4, OUT=64, L=2.
// Fully player-local (edge e: asteroid 64p+j -> player p); 1 block/player, both
// layers fused. Inputs/output are FLOAT32 (established R1-R3). Internal bf16 MFMA.
//
// R4: (1) weight MFMA fragments precomputed into d_ws by prep kernel -> main
// kernel loads them with coalesced 16B vector loads (weights are block-
// invariant; R3 spent ~160 scattered scalar loads/thread/layer);
// (2) wetp LDS array removed (We frags pre-masked in ws) -> LDS 34KB -> 14.8KB;
// (3) asteroid LayerNorm restructured: thread-per-(row,quarter), 2x ds_read_b128
// + xor{1,2} shuffles instead of 16x 64-lane butterflies.

typedef __bf16 bf16x8 __attribute__((ext_vector_type(8)));
typedef float  f32x4  __attribute__((ext_vector_type(4)));

union FragU { unsigned short u[8]; bf16x8 v; };

__device__ __forceinline__ float bf2f(unsigned short u) {
    union { unsigned int i; float f; } v; v.i = ((unsigned int)u) << 16; return v.f;
}
__device__ __forceinline__ unsigned short f2bf(float f) {
    union { float f; unsigned int i; } v; v.f = f;
    unsigned int r = v.i + 0x7fffu + ((v.i >> 16) & 1u);
    return (unsigned short)(r >> 16);
}

#define NEG_SLOPE 0.2f
#define LN_EPS 1e-5f
#define XS 88   // xa row stride in shorts (176B: 16B-aligned, bank-uniform)

struct Smem {
    __align__(16) unsigned short xa[64 * XS];  // cols 0..63 = x, 64..70 = ea, 71 = 0
    float xp[64];
    float xr[256];
    float outp[256];
    float afs[192];
    float rbs[64], gs[64], bs[64];
};

// ---- prep: build per-lane MFMA weight fragments in workspace (block-invariant) ----
__global__ __launch_bounds__(256) void prep_weights(
    const float* __restrict__ Wl, const float* __restrict__ We,
    unsigned short* __restrict__ wlf, unsigned short* __restrict__ wef)
{
    int i = blockIdx.x * 256 + threadIdx.x;      // 128 blocks -> 32768 threads
    {   // Wl fragments: [(layer*8+frag)*256 + t]*8 + jj  (frag = nt*2+ko)
        int jj = i & 7, t = (i >> 3) & 255, frag = (i >> 11) & 7, layer = (i >> 14) & 1;
        int nt = frag >> 1, ko = frag & 1;
        int c = (t >> 6) * 64 + nt * 16 + (t & 15);
        int kb = ko * 32 + ((t >> 4) & 3) * 8;
        wlf[i] = f2bf(Wl[layer * 16384 + (kb + jj) * 256 + c]);
    }
    if (i < 16384) {  // We fragments, pre-zeroed for q!=0 lanes / jj==7
        int jj = i & 7, t = (i >> 3) & 255, nt = (i >> 11) & 3, layer = (i >> 13) & 1;
        int q = (t >> 4) & 3;
        int c = (t >> 6) * 64 + nt * 16 + (t & 15);
        wef[i] = (q == 0 && jj < 7) ? f2bf(We[layer * 1792 + jj * 256 + c])
                                    : (unsigned short)0;
    }
}

template <bool WS>
__global__ __launch_bounds__(256) void gnn_main(
    const float* __restrict__ pf, const float* __restrict__ af,
    const float* __restrict__ eat, const float* __restrict__ Wp,
    const float* __restrict__ bp, const float* __restrict__ Wa,
    const float* __restrict__ ba, const float* __restrict__ Wl,
    const float* __restrict__ bl, const float* __restrict__ Wr,
    const float* __restrict__ br, const float* __restrict__ We,
    const float* __restrict__ att, const float* __restrict__ bias,
    const float* __restrict__ lng, const float* __restrict__ lnb,
    const unsigned short* __restrict__ wlf, const unsigned short* __restrict__ wef,
    float* __restrict__ out)
{
    __shared__ Smem sm;
    const int p = blockIdx.x, t = threadIdx.x;
    const int w = t >> 6, l = t & 63, q = l >> 4, m = l & 15;
    const int cbase = w * 64;

    // ---------- phase 0 ----------
    if (t < 192) sm.afs[t] = af[p * 192 + t];
    if (t < 64) {
        sm.rbs[t] = fmaxf(bias[t], 0.f);   // layer-0 asteroid residual
        sm.gs[t] = lng[t];
        sm.bs[t] = lnb[t];
        float acc = bp[t];
        #pragma unroll
        for (int d = 0; d < 5; ++d) acc += pf[p * 5 + d] * Wp[d * 64 + t];
        sm.xp[t] = fmaxf(acc, 0.f);
    }
    __syncthreads();   // afs ready
    {
        const int k = t & 63;
        float wa0 = Wa[k], wa1 = Wa[64 + k], wa2 = Wa[128 + k], bak = ba[k];
        #pragma unroll
        for (int rep = 0; rep < 16; ++rep) {
            int j = rep * 4 + (t >> 6);
            float acc = bak + sm.afs[j * 3] * wa0 + sm.afs[j * 3 + 1] * wa1
                      + sm.afs[j * 3 + 2] * wa2;
            sm.xa[j * XS + k] = f2bf(fmaxf(acc, 0.f));
        }
    }
    #pragma unroll
    for (int idx = t; idx < 512; idx += 256) {
        int j = idx >> 3, d = idx & 7;
        sm.xa[j * XS + 64 + d] = (d < 7) ? f2bf(eat[(p * 64 + j) * 7 + d])
                                         : (unsigned short)0;
    }
    __syncthreads();

    f32x4 accT[16];

    for (int layer = 0; layer < 2; ++layer) {
        // ---------- xr = xp@Wr + br (coalesced across t) ----------
        {
            float acc = br[layer * 256 + t];
            const float* Wri = Wr + layer * 16384 + t;
            #pragma unroll 16
            for (int k = 0; k < 64; ++k) acc += sm.xp[k] * Wri[k * 256];
            sm.xr[t] = acc;
        }
        __syncthreads();

        // ---------- weight fragments ----------
        FragU bfr[8];
        bf16x8 ebf[4];
        if constexpr (WS) {
            #pragma unroll
            for (int f = 0; f < 8; ++f)
                bfr[f].v = *reinterpret_cast<const bf16x8*>(&wlf[((layer * 8 + f) * 256 + t) * 8]);
            #pragma unroll
            for (int nt = 0; nt < 4; ++nt)
                ebf[nt] = *reinterpret_cast<const bf16x8*>(&wef[((layer * 4 + nt) * 256 + t) * 8]);
        } else {
            const float* Wli = Wl + layer * 16384;
            #pragma unroll
            for (int nt = 0; nt < 4; ++nt) {
                int c = cbase + nt * 16 + m;
                #pragma unroll
                for (int ko = 0; ko < 2; ++ko) {
                    int kb = ko * 32 + q * 8;
                    #pragma unroll
                    for (int jj = 0; jj < 8; ++jj)
                        bfr[nt * 2 + ko].u[jj] = f2bf(Wli[(kb + jj) * 256 + c]);
                }
                FragU e;
                #pragma unroll
                for (int jj = 0; jj < 8; ++jj)
                    e.u[jj] = (q == 0 && jj < 7) ? f2bf(We[layer * 1792 + jj * 256 + c])
                                                 : (unsigned short)0;
                ebf[nt] = e.v;
            }
        }
        float blc[4], xrc[4], aoc[4];
        #pragma unroll
        for (int nt = 0; nt < 4; ++nt) {
            int c = cbase + nt * 16 + m;
            blc[nt] = bl[layer * 256 + c];
            aoc[nt] = att[layer * 256 + c];
            xrc[nt] = sm.xr[c];
        }

        // ---------- MFMA: xl = xa@Wl + bl ; e2 = ea@We + (xr incl br) ----------
        float lp[16];
        #pragma unroll
        for (int i = 0; i < 16; ++i) lp[i] = 0.f;

        #pragma unroll
        for (int mt = 0; mt < 4; ++mt) {
            const int row = mt * 16 + m;
            bf16x8 a0 = *reinterpret_cast<const bf16x8*>(&sm.xa[row * XS + q * 8]);
            bf16x8 a1 = *reinterpret_cast<const bf16x8*>(&sm.xa[row * XS + 32 + q * 8]);
            // e-term A: ea cols (k_local 0..7); q!=0 lanes read same bytes but
            // their B (ebf) is pre-zeroed, so contribution is zero.
            bf16x8 a2 = *reinterpret_cast<const bf16x8*>(&sm.xa[row * XS + 64]);
            #pragma unroll
            for (int nt = 0; nt < 4; ++nt) {
                f32x4 c1 = { blc[nt], blc[nt], blc[nt], blc[nt] };
                c1 = __builtin_amdgcn_mfma_f32_16x16x32_bf16(a0, bfr[nt * 2 + 0].v, c1, 0, 0, 0);
                c1 = __builtin_amdgcn_mfma_f32_16x16x32_bf16(a1, bfr[nt * 2 + 1].v, c1, 0, 0, 0);
                accT[mt * 4 + nt] = c1;   // pure xl(+bl) for messages
                f32x4 c2 = { xrc[nt], xrc[nt], xrc[nt], xrc[nt] };
                c2 = __builtin_amdgcn_mfma_f32_16x16x32_bf16(a2, ebf[nt], c2, 0, 0, 0);
                #pragma unroll
                for (int r = 0; r < 4; ++r) {
                    float ev = c1[r] + c2[r];
                    ev = (ev >= 0.f) ? ev : NEG_SLOPE * ev;
                    lp[mt * 4 + r] += ev * aoc[nt];
                }
            }
        }

        // att-dot: reduce over the 16 m-lanes; lp[i] -> logit[j = mt*16+q*4+r]
        #pragma unroll
        for (int i = 0; i < 16; ++i) {
            float v = lp[i];
            v += __shfl_xor(v, 1, 64);
            v += __shfl_xor(v, 2, 64);
            v += __shfl_xor(v, 4, 64);
            v += __shfl_xor(v, 8, 64);
            lp[i] = v;
        }
        // softmax over all 64 j
        float mx = lp[0];
        #pragma unroll
        for (int i = 1; i < 16; ++i) mx = fmaxf(mx, lp[i]);
        mx = fmaxf(mx, __shfl_xor(mx, 16, 64));
        mx = fmaxf(mx, __shfl_xor(mx, 32, 64));
        float den = 0.f;
        #pragma unroll
        for (int i = 0; i < 16; ++i) { lp[i] = __expf(lp[i] - mx); den += lp[i]; }
        den += __shfl_xor(den, 16, 64);
        den += __shfl_xor(den, 32, 64);
        const float rden = 1.f / den;

        // weighted message sum: out[w][c] = sum_j alpha[j] * xl[j][c]
        #pragma unroll
        for (int nt = 0; nt < 4; ++nt) {
            float s = 0.f;
            #pragma unroll
            for (int mt = 0; mt < 4; ++mt) {
                f32x4 c = accT[mt * 4 + nt];
                #pragma unroll
                for (int r = 0; r < 4; ++r) s += lp[mt * 4 + r] * c[r];
            }
            s *= rden;
            s += __shfl_xor(s, 16, 64);
            s += __shfl_xor(s, 32, 64);
            if (q == 0) sm.outp[cbase + nt * 16 + m] = s;
        }
        __syncthreads();

        // ---------- asteroid update (only needed after layer 0) ----------
        if (layer == 0) {
            const int j = t >> 2, part = t & 3;
            unsigned short* rowp = &sm.xa[j * XS + part * 16];
            FragU A0, A1;
            A0.v = *reinterpret_cast<const bf16x8*>(rowp);
            A1.v = *reinterpret_cast<const bf16x8*>(rowp + 8);
            float v[16], sum = 0.f, sq = 0.f;
            #pragma unroll
            for (int i = 0; i < 16; ++i) {
                unsigned short us = (i < 8) ? A0.u[i] : A1.u[i - 8];
                float x = bf2f(us) + sm.rbs[part * 16 + i];
                v[i] = x; sum += x; sq += x * x;
            }
            sum += __shfl_xor(sum, 1, 64); sq += __shfl_xor(sq, 1, 64);
            sum += __shfl_xor(sum, 2, 64); sq += __shfl_xor(sq, 2, 64);
            float mu = sum * (1.f / 64.f);
            float var = sq * (1.f / 64.f) - mu * mu;
            float rs = rsqrtf(var + LN_EPS);
            FragU O0, O1;
            #pragma unroll
            for (int i = 0; i < 16; ++i) {
                int col = part * 16 + i;
                float y = (v[i] - mu) * rs * sm.gs[col] + sm.bs[col];
                unsigned short ub = f2bf(y);
                if (i < 8) O0.u[i] = ub; else O1.u[i - 8] = ub;
            }
            *reinterpret_cast<bf16x8*>(rowp) = O0.v;
            *reinterpret_cast<bf16x8*>(rowp + 8) = O1.v;
        }
        // ---------- player update ----------
        if (t < 64) {
            float xnew = 0.25f * (sm.outp[t] + sm.outp[64 + t] + sm.outp[128 + t] + sm.outp[192 + t])
                       + bias[layer * 64 + t];
            float v = sm.xp[t] + fmaxf(xnew, 0.f);
            float sum = v, sq = v * v;
            #pragma unroll
            for (int msk = 1; msk <= 32; msk <<= 1) {
                sum += __shfl_xor(sum, msk, 64);
                sq  += __shfl_xor(sq,  msk, 64);
            }
            float mu = sum * (1.f / 64.f);
            float var = sq * (1.f / 64.f) - mu * mu;
            float y = (v - mu) * rsqrtf(var + LN_EPS) * lng[layer * 64 + t]
                    + lnb[layer * 64 + t];
            sm.xp[t] = y;
        }
        __syncthreads();
    }

    if (t < 64) out[p * 64 + t] = sm.xp[t];
}

extern "C" void kernel_launch(void* const* d_in, const int* in_sizes, int n_in,
                              void* d_out, int out_size, void* d_ws, size_t ws_size,
                              hipStream_t stream) {
    const float* pf   = (const float*)d_in[0];
    const float* af   = (const float*)d_in[1];
    // d_in[2] = edge_index (int32): src=arange(E), dst=src//64 — structural, unused.
    const float* eat  = (const float*)d_in[3];
    const float* Wp   = (const float*)d_in[4];
    const float* bp   = (const float*)d_in[5];
    const float* Wa   = (const float*)d_in[6];
    const float* ba   = (const float*)d_in[7];
    const float* Wl   = (const float*)d_in[8];
    const float* bl   = (const float*)d_in[9];
    const float* Wr   = (const float*)d_in[10];
    const float* br   = (const float*)d_in[11];
    const float* We   = (const float*)d_in[12];
    const float* att  = (const float*)d_in[13];
    const float* bias = (const float*)d_in[14];
    const float* lng  = (const float*)d_in[15];
    const float* lnb  = (const float*)d_in[16];
    float* out = (float*)d_out;

    const int B = in_sizes[0] / 5;  // 4096 players
    unsigned short* wlf = (unsigned short*)d_ws;        // 32768 shorts (64KB)
    unsigned short* wef = wlf + 32768;                  // 16384 shorts (32KB)
    const size_t need = 98304;

    if (ws_size >= need) {
        prep_weights<<<dim3(128), dim3(256), 0, stream>>>(Wl, We, wlf, wef);
        gnn_main<true><<<dim3(B), dim3(256), 0, stream>>>(
            pf, af, eat, Wp, bp, Wa, ba, Wl, bl, Wr, br, We, att, bias, lng, lnb,
            wlf, wef, out);
    } else {
        gnn_main<false><<<dim3(B), dim3(256), 0, stream>>>(
            pf, af, eat, Wp, bp, Wa, ba, Wl, bl, Wr, br, We, att, bias, lng, lnb,
            wlf, wef, out);
    }
}

// Round 6
// 181.655 us; speedup vs baseline: 1.7458x; 1.1184x over previous
//
#include <hip/hip_runtime.h>

// GNNBackbone: B=4096 players, 64 asteroids each, HID=64, HEADS=4, OUT=64, L=2.
// Fully player-local (edge e: asteroid 64p+j -> player p); 1 block/player, both
// layers fused. Inputs/output FLOAT32 (established R1-R3). Internal bf16 MFMA.
//
// R6: fixes R5's compiler-level intra-wave LDS races:
//  - xr via MFMA kept, but NO LDS round-trip: broadcast-A makes all D rows
//    bitwise identical, so every lane reads xr[c] from its own cx[0].
//  - lp/alpha LDS round-trips now cross __syncthreads() (lanes are threads in
//    the LLVM model; wave-local LDS comms without a barrier are UB).
//  - lp buffer stride 17: exact 2-way bank aliasing (free on CDNA4).

typedef __bf16 bf16x8 __attribute__((ext_vector_type(8)));
typedef float  f32x4  __attribute__((ext_vector_type(4)));

union FragU { unsigned short u[8]; bf16x8 v; };

__device__ __forceinline__ float bf2f(unsigned short u) {
    union { unsigned int i; float f; } v; v.i = ((unsigned int)u) << 16; return v.f;
}
__device__ __forceinline__ unsigned short f2bf(float f) {
    union { __bf16 b; unsigned short u; } x; x.b = (__bf16)f; return x.u;
}

#define NEG_SLOPE 0.2f
#define LN_EPS 1e-5f
#define XS 88     // xa row stride in shorts (176B, 16B-aligned)
#define LPS 17    // lp buffer stride (floats): 2-way bank aliasing only

struct Smem {
    __align__(16) unsigned short xa[64 * XS];   // cols 0..63 = x, 64..70 = ea, 71 = 0
    __align__(16) unsigned short xpb[64];       // xp as bf16 (xr MFMA A-operand)
    float lpb[4 * 64 * LPS];                    // per-head logit partials [j][m]
    float alf[256];                             // per-head alpha[j]
    float outp[256];
    float xp[64];
    float afs[192];
    float rbs[64], gs[64], bs[64];
    float sbl[256], satt[256], sbr[256];
};

// ---- prep: per-lane MFMA weight fragments in workspace (block-invariant) ----
__global__ __launch_bounds__(256) void prep_weights(
    const float* __restrict__ Wl, const float* __restrict__ Wr,
    const float* __restrict__ We,
    unsigned short* __restrict__ wlf, unsigned short* __restrict__ wrf,
    unsigned short* __restrict__ wef)
{
    int i = blockIdx.x * 256 + threadIdx.x;   // 128 blocks -> 32768 threads
    int jj = i & 7, t = (i >> 3) & 255, frag = (i >> 11) & 7, layer = (i >> 14) & 1;
    int nt = frag >> 1, ko = frag & 1;
    int c = (t >> 6) * 64 + nt * 16 + (t & 15);
    int kb = ko * 32 + ((t >> 4) & 3) * 8;
    wlf[i] = f2bf(Wl[layer * 16384 + (kb + jj) * 256 + c]);
    wrf[i] = f2bf(Wr[layer * 16384 + (kb + jj) * 256 + c]);
    if (i < 16384) {   // We frags, pre-zeroed for q!=0 lanes / jj==7
        int j2 = i & 7, t2 = (i >> 3) & 255, n2 = (i >> 11) & 3, l2 = (i >> 13) & 1;
        int q2 = (t2 >> 4) & 3;
        int c2 = (t2 >> 6) * 64 + n2 * 16 + (t2 & 15);
        wef[i] = (q2 == 0 && j2 < 7) ? f2bf(We[l2 * 1792 + j2 * 256 + c2])
                                     : (unsigned short)0;
    }
}

template <bool WS>
__global__ __launch_bounds__(256) void gnn_main(
    const float* __restrict__ pf, const float* __restrict__ af,
    const float* __restrict__ eat, const float* __restrict__ Wp,
    const float* __restrict__ bp, const float* __restrict__ Wa,
    const float* __restrict__ ba, const float* __restrict__ Wl,
    const float* __restrict__ bl, const float* __restrict__ Wr,
    const float* __restrict__ br, const float* __restrict__ We,
    const float* __restrict__ att, const float* __restrict__ bias,
    const float* __restrict__ lng, const float* __restrict__ lnb,
    const unsigned short* __restrict__ wlf, const unsigned short* __restrict__ wrf,
    const unsigned short* __restrict__ wef, float* __restrict__ out)
{
    __shared__ Smem sm;
    const int p = blockIdx.x, t = threadIdx.x;
    const int w = t >> 6, l = t & 63, q = l >> 4, m = l & 15;
    const int cbase = w * 64;

    // ---------- phase 0 ----------
    if (t < 192) sm.afs[t] = af[p * 192 + t];
    if (t < 64) {
        sm.rbs[t] = fmaxf(bias[t], 0.f);
        sm.gs[t] = lng[t];
        sm.bs[t] = lnb[t];
        float acc = bp[t];
        #pragma unroll
        for (int d = 0; d < 5; ++d) acc += pf[p * 5 + d] * Wp[d * 64 + t];
        float xp0 = fmaxf(acc, 0.f);
        sm.xp[t] = xp0;
        sm.xpb[t] = f2bf(xp0);
    }
    __syncthreads();
    {
        const int k = t & 63;
        float wa0 = Wa[k], wa1 = Wa[64 + k], wa2 = Wa[128 + k], bak = ba[k];
        #pragma unroll
        for (int rep = 0; rep < 16; ++rep) {
            int j = rep * 4 + (t >> 6);
            float acc = bak + sm.afs[j * 3] * wa0 + sm.afs[j * 3 + 1] * wa1
                      + sm.afs[j * 3 + 2] * wa2;
            sm.xa[j * XS + k] = f2bf(fmaxf(acc, 0.f));
        }
    }
    #pragma unroll
    for (int idx = t; idx < 512; idx += 256) {
        int j = idx >> 3, d = idx & 7;
        sm.xa[j * XS + 64 + d] = (d < 7) ? f2bf(eat[(p * 64 + j) * 7 + d])
                                         : (unsigned short)0;
    }

    f32x4 accT[16];

    for (int layer = 0; layer < 2; ++layer) {
        // ---------- stage per-layer scalars (coalesced) ----------
        sm.sbl[t]  = bl[layer * 256 + t];
        sm.satt[t] = att[layer * 256 + t];
        sm.sbr[t]  = br[layer * 256 + t];
        __syncthreads();   // also covers phase-0 xa / prior-layer xpb,xa writes

        // ---------- xr = xp @ Wr + br via MFMA, kept in registers ----------
        // A = xp broadcast to all 16 rows => all D rows bitwise identical;
        // every lane holds xr[c=cbase+nt*16+m] in cx[0]. No LDS round-trip.
        float xrc[4];
        {
            FragU xf0, xf1;
            xf0.v = *reinterpret_cast<const bf16x8*>(&sm.xpb[q * 8]);
            xf1.v = *reinterpret_cast<const bf16x8*>(&sm.xpb[32 + q * 8]);
            #pragma unroll
            for (int nt = 0; nt < 4; ++nt) {
                int c = cbase + nt * 16 + m;
                FragU r0, r1;
                if constexpr (WS) {
                    r0.v = *reinterpret_cast<const bf16x8*>(&wrf[((layer * 8 + nt * 2 + 0) * 256 + t) * 8]);
                    r1.v = *reinterpret_cast<const bf16x8*>(&wrf[((layer * 8 + nt * 2 + 1) * 256 + t) * 8]);
                } else {
                    #pragma unroll
                    for (int jj = 0; jj < 8; ++jj) {
                        r0.u[jj] = f2bf(Wr[layer * 16384 + (q * 8 + jj) * 256 + c]);
                        r1.u[jj] = f2bf(Wr[layer * 16384 + (32 + q * 8 + jj) * 256 + c]);
                    }
                }
                float sb = sm.sbr[c];
                f32x4 cx = { sb, sb, sb, sb };
                cx = __builtin_amdgcn_mfma_f32_16x16x32_bf16(xf0.v, r0.v, cx, 0, 0, 0);
                cx = __builtin_amdgcn_mfma_f32_16x16x32_bf16(xf1.v, r1.v, cx, 0, 0, 0);
                xrc[nt] = cx[0];
            }
        }

        // ---------- weight fragments ----------
        FragU bfr[8];
        bf16x8 ebf[4];
        if constexpr (WS) {
            #pragma unroll
            for (int f = 0; f < 8; ++f)
                bfr[f].v = *reinterpret_cast<const bf16x8*>(&wlf[((layer * 8 + f) * 256 + t) * 8]);
            #pragma unroll
            for (int nt = 0; nt < 4; ++nt)
                ebf[nt] = *reinterpret_cast<const bf16x8*>(&wef[((layer * 4 + nt) * 256 + t) * 8]);
        } else {
            const float* Wli = Wl + layer * 16384;
            #pragma unroll
            for (int nt = 0; nt < 4; ++nt) {
                int c = cbase + nt * 16 + m;
                #pragma unroll
                for (int ko = 0; ko < 2; ++ko) {
                    int kb = ko * 32 + q * 8;
                    #pragma unroll
                    for (int jj = 0; jj < 8; ++jj)
                        bfr[nt * 2 + ko].u[jj] = f2bf(Wli[(kb + jj) * 256 + c]);
                }
                FragU e;
                #pragma unroll
                for (int jj = 0; jj < 8; ++jj)
                    e.u[jj] = (q == 0 && jj < 7) ? f2bf(We[layer * 1792 + jj * 256 + c])
                                                 : (unsigned short)0;
                ebf[nt] = e.v;
            }
        }
        float blc[4], aoc[4];
        #pragma unroll
        for (int nt = 0; nt < 4; ++nt) {
            int c = cbase + nt * 16 + m;
            blc[nt] = sm.sbl[c];
            aoc[nt] = sm.satt[c];
        }

        // ---------- MFMA: xl = xa@Wl + bl ; e2 = ea@We + (xr incl br) ----------
        float lp[16];
        #pragma unroll
        for (int i = 0; i < 16; ++i) lp[i] = 0.f;

        #pragma unroll
        for (int mt = 0; mt < 4; ++mt) {
            const int row = mt * 16 + m;
            bf16x8 a0 = *reinterpret_cast<const bf16x8*>(&sm.xa[row * XS + q * 8]);
            bf16x8 a1 = *reinterpret_cast<const bf16x8*>(&sm.xa[row * XS + 32 + q * 8]);
            bf16x8 a2 = *reinterpret_cast<const bf16x8*>(&sm.xa[row * XS + 64]);
            #pragma unroll
            for (int nt = 0; nt < 4; ++nt) {
                f32x4 c1 = { blc[nt], blc[nt], blc[nt], blc[nt] };
                c1 = __builtin_amdgcn_mfma_f32_16x16x32_bf16(a0, bfr[nt * 2 + 0].v, c1, 0, 0, 0);
                c1 = __builtin_amdgcn_mfma_f32_16x16x32_bf16(a1, bfr[nt * 2 + 1].v, c1, 0, 0, 0);
                accT[mt * 4 + nt] = c1;   // pure xl(+bl) for messages
                f32x4 c2 = { xrc[nt], xrc[nt], xrc[nt], xrc[nt] };
                c2 = __builtin_amdgcn_mfma_f32_16x16x32_bf16(a2, ebf[nt], c2, 0, 0, 0);
                #pragma unroll
                for (int r = 0; r < 4; ++r) {
                    float ev = c1[r] + c2[r];
                    ev = fmaxf(ev, NEG_SLOPE * ev);   // LeakyReLU (slope<1)
                    lp[mt * 4 + r] += ev * aoc[nt];
                }
            }
        }

        // ---------- att-dot partials -> LDS; barrier; per-j sum + softmax ----------
        {
            float* lpw = &sm.lpb[w * 64 * LPS];
            #pragma unroll
            for (int mt = 0; mt < 4; ++mt)
                #pragma unroll
                for (int r = 0; r < 4; ++r)
                    lpw[(mt * 16 + q * 4 + r) * LPS + m] = lp[mt * 4 + r];
        }
        __syncthreads();   // cross-lane LDS comm must cross a barrier (R5 bug)
        {
            const float* lpw = &sm.lpb[w * 64 * LPS];
            float lg = 0.f;
            #pragma unroll
            for (int mm = 0; mm < 16; ++mm) lg += lpw[l * LPS + mm];
            float mx = lg;
            #pragma unroll
            for (int msk = 1; msk <= 32; msk <<= 1) mx = fmaxf(mx, __shfl_xor(mx, msk, 64));
            float al = __expf(lg - mx);
            float den = al;
            #pragma unroll
            for (int msk = 1; msk <= 32; msk <<= 1) den += __shfl_xor(den, msk, 64);
            sm.alf[w * 64 + l] = al / den;
        }
        __syncthreads();   // alpha visible to all lanes

        // ---------- weighted message sum ----------
        {
            const float* alw = &sm.alf[w * 64];
            float al16[16];
            #pragma unroll
            for (int mt = 0; mt < 4; ++mt)
                #pragma unroll
                for (int r = 0; r < 4; ++r)
                    al16[mt * 4 + r] = alw[mt * 16 + q * 4 + r];
            #pragma unroll
            for (int nt = 0; nt < 4; ++nt) {
                float s = 0.f;
                #pragma unroll
                for (int i = 0; i < 16; ++i) s += al16[i] * accT[(i >> 2) * 4 + nt][i & 3];
                s += __shfl_xor(s, 16, 64);
                s += __shfl_xor(s, 32, 64);
                if (q == 0) sm.outp[cbase + nt * 16 + m] = s;
            }
        }
        __syncthreads();

        // ---------- asteroid update (only needed after layer 0) ----------
        if (layer == 0) {
            const int j = t >> 2, part = t & 3;
            unsigned short* rowp = &sm.xa[j * XS + part * 16];
            FragU A0, A1;
            A0.v = *reinterpret_cast<const bf16x8*>(rowp);
            A1.v = *reinterpret_cast<const bf16x8*>(rowp + 8);
            float v[16], sum = 0.f, sq = 0.f;
            #pragma unroll
            for (int i = 0; i < 16; ++i) {
                unsigned short us = (i < 8) ? A0.u[i] : A1.u[i - 8];
                float x = bf2f(us) + sm.rbs[part * 16 + i];
                v[i] = x; sum += x; sq += x * x;
            }
            sum += __shfl_xor(sum, 1, 64); sq += __shfl_xor(sq, 1, 64);
            sum += __shfl_xor(sum, 2, 64); sq += __shfl_xor(sq, 2, 64);
            float mu = sum * (1.f / 64.f);
            float var = sq * (1.f / 64.f) - mu * mu;
            float rs = rsqrtf(var + LN_EPS);
            FragU O0, O1;
            #pragma unroll
            for (int i = 0; i < 16; ++i) {
                int col = part * 16 + i;
                unsigned short ub = f2bf((v[i] - mu) * rs * sm.gs[col] + sm.bs[col]);
                if (i < 8) O0.u[i] = ub; else O1.u[i - 8] = ub;
            }
            *reinterpret_cast<bf16x8*>(rowp) = O0.v;
            *reinterpret_cast<bf16x8*>(rowp + 8) = O1.v;
        }
        // ---------- player update ----------
        if (t < 64) {
            float xnew = 0.25f * (sm.outp[t] + sm.outp[64 + t] + sm.outp[128 + t] + sm.outp[192 + t])
                       + bias[layer * 64 + t];
            float v = sm.xp[t] + fmaxf(xnew, 0.f);
            float sum = v, sq = v * v;
            #pragma unroll
            for (int msk = 1; msk <= 32; msk <<= 1) {
                sum += __shfl_xor(sum, msk, 64);
                sq  += __shfl_xor(sq,  msk, 64);
            }
            float mu = sum * (1.f / 64.f);
            float var = sq * (1.f / 64.f) - mu * mu;
            float y = (v - mu) * rsqrtf(var + LN_EPS) * lng[layer * 64 + t]
                    + lnb[layer * 64 + t];
            sm.xp[t] = y;
            sm.xpb[t] = f2bf(y);
        }
        __syncthreads();
    }

    if (t < 64) out[p * 64 + t] = sm.xp[t];
}

extern "C" void kernel_launch(void* const* d_in, const int* in_sizes, int n_in,
                              void* d_out, int out_size, void* d_ws, size_t ws_size,
                              hipStream_t stream) {
    const float* pf   = (const float*)d_in[0];
    const float* af   = (const float*)d_in[1];
    // d_in[2] = edge_index (int32): src=arange(E), dst=src//64 — structural, unused.
    const float* eat  = (const float*)d_in[3];
    const float* Wp   = (const float*)d_in[4];
    const float* bp   = (const float*)d_in[5];
    const float* Wa   = (const float*)d_in[6];
    const float* ba   = (const float*)d_in[7];
    const float* Wl   = (const float*)d_in[8];
    const float* bl   = (const float*)d_in[9];
    const float* Wr   = (const float*)d_in[10];
    const float* br   = (const float*)d_in[11];
    const float* We   = (const float*)d_in[12];
    const float* att  = (const float*)d_in[13];
    const float* bias = (const float*)d_in[14];
    const float* lng  = (const float*)d_in[15];
    const float* lnb  = (const float*)d_in[16];
    float* out = (float*)d_out;

    const int B = in_sizes[0] / 5;  // 4096 players
    unsigned short* wlf = (unsigned short*)d_ws;   // 32768 shorts
    unsigned short* wrf = wlf + 32768;             // 32768 shorts
    unsigned short* wef = wrf + 32768;             // 16384 shorts
    const size_t need = (32768 + 32768 + 16384) * sizeof(unsigned short);

    if (ws_size >= need) {
        prep_weights<<<dim3(128), dim3(256), 0, stream>>>(Wl, Wr, We, wlf, wrf, wef);
        gnn_main<true><<<dim3(B), dim3(256), 0, stream>>>(
            pf, af, eat, Wp, bp, Wa, ba, Wl, bl, Wr, br, We, att, bias, lng, lnb,
            wlf, wrf, wef, out);
    } else {
        gnn_main<false><<<dim3(B), dim3(256), 0, stream>>>(
            pf, af, eat, Wp, bp, Wa, ba, Wl, bl, Wr, br, We, att, bias, lng, lnb,
            wlf, wrf, wef, out);
    }
}